// Round 4
// baseline (426.333 us; speedup 1.0000x reference)
//
#include <hip/hip_runtime.h>

// Fused GraphVertResOutModel for MI355X (gfx950), bf16 MFMA everywhere.
// One workgroup per batch (512 blocks x 512 threads = 8 waves).
// LDS: bufA (x / h, row-major [256][128] bf16, swizzled)  64KB
//      bufB (y col-major [128][256] / h ping-pong)        64KB
//      wls  (current weight matrix [128][128] bf16)       32KB
// MFMA v_mfma_f32_16x16x32_bf16:
//   A-frag: row = lane&15, cols = (lane>>4)*8 + 0..7
//   B-frag: col = lane&15, rows = (lane>>4)*8 + 0..7
//   D:      col = lane&15, row = (lane>>4)*4 + reg   (measured, learn_hip m89/m91)
// R1: G0 fragments loaded once (layer-invariant), reused all 4 layers.
// R2: (a) T14 async weight staging; (b) MLP swapped operands (A=W, B=h) ->
//     row-major D, contiguous us4 stores.
// R3: f1 loop single-barrier: store chunk c+1 into the NOT-currently-read
//     weight buffer concurrently with MFMA compute (two buffers already
//     exist), one barrier per chunk instead of two. Next planned (after a
//     green bench): (gn4,gp2) wave grid to cut 8x cross-wave W re-reads
//     (theory says kernel is LDS-read-bound: ~8.5MB LDS reads/block).

typedef __attribute__((ext_vector_type(8))) __bf16 bf16x8;
typedef __attribute__((ext_vector_type(4))) float f32x4;
typedef __attribute__((ext_vector_type(4))) unsigned short us4;
typedef __attribute__((ext_vector_type(8))) unsigned short us8;

#define MFMA16(a, b, c) __builtin_amdgcn_mfma_f32_16x16x32_bf16((a), (b), (c), 0, 0, 0)

__device__ __forceinline__ unsigned short f2bf(float f) {
  unsigned u = __float_as_uint(f);
  return (unsigned short)((u + 0x7fffu + ((u >> 16) & 1u)) >> 16);  // RNE
}
__device__ __forceinline__ float bf2f(unsigned short s) {
  return __uint_as_float(((unsigned)s) << 16);
}
__device__ __forceinline__ bf16x8 asb(us8 u) { return __builtin_bit_cast(bf16x8, u); }

__device__ __forceinline__ us8 cvt8(f32x4 a, f32x4 c) {
  us8 r;
  r[0] = f2bf(a[0]); r[1] = f2bf(a[1]); r[2] = f2bf(a[2]); r[3] = f2bf(a[3]);
  r[4] = f2bf(c[0]); r[5] = f2bf(c[1]); r[6] = f2bf(c[2]); r[7] = f2bf(c[3]);
  return r;
}

__device__ __forceinline__ bf16x8 lds_frag(const unsigned short* p) {
  return asb(*reinterpret_cast<const us8*>(p));
}

// Weight staging, split for async overlap (T14): load issues early into regs,
// store (cvt + ds_write, swizzled) runs later, overlapped where possible.
struct WReg { f32x4 a[4]; f32x4 b[4]; };

__device__ __forceinline__ void stage_load(WReg& w, const float* __restrict__ src, int tid) {
#pragma unroll
  for (int it = 0; it < 4; ++it) {
    int o = tid + it * 512;
    int p = o >> 4;
    int f = (o & 15) << 3;
    const float* s = src + p * 128 + f;
    w.a[it] = *reinterpret_cast<const f32x4*>(s);
    w.b[it] = *reinterpret_cast<const f32x4*>(s + 4);
  }
}

__device__ __forceinline__ void stage_store(const WReg& w, unsigned short* dst, int tid) {
#pragma unroll
  for (int it = 0; it < 4; ++it) {
    int o = tid + it * 512;
    int p = o >> 4;
    int f = (o & 15) << 3;
    *reinterpret_cast<us8*>(&dst[p * 128 + (f ^ ((p & 7) << 3))]) = cvt8(w.a[it], w.b[it]);
  }
}

__global__ __launch_bounds__(512, 2)
void fused_model(const float* __restrict__ G, const float* __restrict__ xG,
                 const float* __restrict__ gmlW, const float* __restrict__ gmlb,
                 const float* __restrict__ lin0W, const float* __restrict__ lin0b,
                 const float* __restrict__ rinW, const float* __restrict__ rinb,
                 const float* __restrict__ rb1W, const float* __restrict__ rb1b,
                 const float* __restrict__ rb2W,
                 const float* __restrict__ routW, const float* __restrict__ routb,
                 const float* __restrict__ f1W, const float* __restrict__ f1b,
                 const float* __restrict__ f2W, const float* __restrict__ f2b,
                 float* __restrict__ out)
{
  __shared__ __align__(16) unsigned short bufA[256 * 128];  // 64KB
  __shared__ __align__(16) unsigned short bufB[256 * 128];  // 64KB
  __shared__ __align__(16) unsigned short wls[128 * 128];   // 32KB

  const int tid = (int)threadIdx.x;
  const int b = (int)blockIdx.x;
  const int wv = tid >> 6;        // wave 0..7, owns rows [wv*32, wv*32+32)
  const int lane = tid & 63;
  const int lr = lane & 15;
  const int lg = lane >> 4;

  const f32x4 zero4 = {0.f, 0.f, 0.f, 0.f};
  WReg wreg;

  // ---------------- stage x_G -> bufA (row-major bf16, swizzled) -------------
  {
    const float* xb = xG + (size_t)b * (256 * 128);
#pragma unroll
    for (int it = 0; it < 8; ++it) {
      int o = tid + it * 512;
      int n = o >> 4;
      int f = (o & 15) << 3;
      const float* s = xb + n * 128 + f;
      f32x4 x0 = *reinterpret_cast<const f32x4*>(s);
      f32x4 x1 = *reinterpret_cast<const f32x4*>(s + 4);
      *reinterpret_cast<us8*>(&bufA[n * 128 + (f ^ ((n & 7) << 3))]) = cvt8(x0, x1);
    }
  }
  // layer-0 weights (prologue: nothing to overlap with)
  stage_load(wreg, gmlW, tid);
  stage_store(wreg, wls, tid);

  // ---------------- G0 fragments: load ONCE, reuse for all 4 layers ----------
  const float* Gb = G + (size_t)b * (256 * 256);
  bf16x8 bg[2][8];
#pragma unroll
  for (int mt = 0; mt < 2; ++mt) {
    int m = wv * 32 + mt * 16 + lr;
    const float* grow = Gb + (size_t)m * 256;
#pragma unroll
    for (int ks = 0; ks < 8; ++ks) {
      const float* s = grow + ks * 32 + lg * 8;
      f32x4 x0 = *reinterpret_cast<const f32x4*>(s);
      f32x4 x1 = *reinterpret_cast<const f32x4*>(s + 4);
      bg[mt][ks] = asb(cvt8(x0, x1));
    }
  }
  __syncthreads();

  // ---------------- 4 graph layers -------------------------------------------
#pragma unroll 1
  for (int l = 0; l < 4; ++l) {
    // ---- step A: y = x @ W^T + b   -> bufB as y_cm[p][n] (col-major, swizzled)
    {
      bf16x8 a[2][4];
#pragma unroll
      for (int nt = 0; nt < 2; ++nt) {
        int n = wv * 32 + nt * 16 + lr;
#pragma unroll
        for (int k = 0; k < 4; ++k)
          a[nt][k] = lds_frag(&bufA[n * 128 + ((k * 32 + lg * 8) ^ ((n & 7) << 3))]);
      }
      const float* bias = gmlb + l * 128;
#pragma unroll
      for (int ptg = 0; ptg < 8; ptg += 4) {
        f32x4 acc[4][2];
#pragma unroll
        for (int j = 0; j < 4; ++j) { acc[j][0] = zero4; acc[j][1] = zero4; }
#pragma unroll
        for (int k = 0; k < 4; ++k) {
#pragma unroll
          for (int j = 0; j < 4; ++j) {
            int p = (ptg + j) * 16 + lr;
            bf16x8 bw = lds_frag(&wls[p * 128 + ((k * 32 + lg * 8) ^ ((p & 7) << 3))]);
            acc[j][0] = MFMA16(a[0][k], bw, acc[j][0]);
            acc[j][1] = MFMA16(a[1][k], bw, acc[j][1]);
          }
        }
#pragma unroll
        for (int j = 0; j < 4; ++j) {
          int p = (ptg + j) * 16 + lr;
          float bv = bias[p];
#pragma unroll
          for (int nt = 0; nt < 2; ++nt) {
            int nb = wv * 32 + nt * 16 + lg * 4;
            us4 pk;
#pragma unroll
            for (int r = 0; r < 4; ++r) pk[r] = f2bf(acc[j][nt][r] + bv);
            *reinterpret_cast<us4*>(&bufB[p * 256 + (nb ^ ((p & 7) << 3))]) = pk;
          }
        }
      }
    }
    __syncthreads();

    // issue next weight loads NOW -> latency hides under step B's MFMAs
    stage_load(wreg, (l < 3) ? (gmlW + (l + 1) * 16384) : lin0W, tid);

    // ---- step B: x = relu(G0 @ y) -> bufA (row-major, swizzled)
    // x^T[p][m] = sum_n y_cm[p][n] * G0[m][n]  (A = y^T, B = G0 rows)
    {
#pragma unroll
      for (int ptg = 0; ptg < 8; ptg += 2) {
        bf16x8 ya[2][8];
#pragma unroll
        for (int j = 0; j < 2; ++j) {
          int p = (ptg + j) * 16 + lr;
#pragma unroll
          for (int ks = 0; ks < 8; ++ks)
            ya[j][ks] = lds_frag(&bufB[p * 256 + ((ks * 32 + lg * 8) ^ ((p & 7) << 3))]);
        }
        f32x4 acc[2][2];
        acc[0][0] = zero4; acc[0][1] = zero4; acc[1][0] = zero4; acc[1][1] = zero4;
#pragma unroll
        for (int ks = 0; ks < 8; ++ks) {
#pragma unroll
          for (int j = 0; j < 2; ++j) {
            acc[j][0] = MFMA16(ya[j][ks], bg[0][ks], acc[j][0]);
            acc[j][1] = MFMA16(ya[j][ks], bg[1][ks], acc[j][1]);
          }
        }
#pragma unroll
        for (int j = 0; j < 2; ++j) {
#pragma unroll
          for (int mt = 0; mt < 2; ++mt) {
            int m = wv * 32 + mt * 16 + lr;
            int pb = (ptg + j) * 16 + lg * 4;
            us4 pk;
#pragma unroll
            for (int r = 0; r < 4; ++r) {
              float v = acc[j][mt][r];
              v = v > 0.f ? v : 0.f;
              pk[r] = f2bf(v);
            }
            *reinterpret_cast<us4*>(&bufA[m * 128 + (pb ^ ((m & 7) << 3))]) = pk;
          }
        }
      }
    }
    stage_store(wreg, wls, tid);  // wls not read since step A's barrier
    __syncthreads();
  }

  // ---------------- MLP chain: 9 ops of [256x128] @ [128x128]^T ---------------
  // even ops: bufA -> bufB ; odd ops: bufB -> bufA
  // op: 0=lin0(+b) 1=rin(+b) 2/4/6=rb1(+b,relu) 3/5/7=rb2(resid) 8=rout(+b)
  // wls already holds lin0W; pipeline: compute(op) -> store W[op+1] -> load W[op+2]
  stage_load(wreg, rinW, tid);
#pragma unroll 1
  for (int op = 0; op < 9; ++op) {
    const float* bp;
    const float* wn;               // W[op+2] to prefetch
    bool rl = false, rs = false;
    switch (op) {
      case 0: bp = lin0b;      wn = rb1W;          break;
      case 1: bp = rinb;       wn = rb2W;          break;
      case 2: bp = rb1b;       wn = rb1W + 16384;  rl = true; break;
      case 3: bp = nullptr;    wn = rb2W + 16384;  rs = true; break;
      case 4: bp = rb1b + 128; wn = rb1W + 32768;  rl = true; break;
      case 5: bp = nullptr;    wn = rb2W + 32768;  rs = true; break;
      case 6: bp = rb1b + 256; wn = routW;         rl = true; break;
      case 7: bp = nullptr;    wn = f1W;           rs = true; break;
      default: bp = routb;     wn = nullptr;       break;
    }
    const unsigned short* s = (op & 1) ? bufB : bufA;
    unsigned short* d = (op & 1) ? bufA : bufB;

    // ---- compute: h' = h @ W^T (+bias/relu/residual), swapped operands:
    // A = W (rows p), B = h (cols n) -> D[p][n]: lane col = n, rows = p contig.
    bf16x8 hb[2][4];
#pragma unroll
    for (int nt = 0; nt < 2; ++nt) {
      int n = wv * 32 + nt * 16 + lr;
#pragma unroll
      for (int k = 0; k < 4; ++k)
        hb[nt][k] = lds_frag(&s[n * 128 + ((k * 32 + lg * 8) ^ ((n & 7) << 3))]);
    }
#pragma unroll
    for (int ptg = 0; ptg < 8; ptg += 4) {
      f32x4 acc[4][2];
#pragma unroll
      for (int j = 0; j < 4; ++j) { acc[j][0] = zero4; acc[j][1] = zero4; }
#pragma unroll
      for (int k = 0; k < 4; ++k) {
#pragma unroll
        for (int j = 0; j < 4; ++j) {
          int p = (ptg + j) * 16 + lr;
          bf16x8 aw = lds_frag(&wls[p * 128 + ((k * 32 + lg * 8) ^ ((p & 7) << 3))]);
          acc[j][0] = MFMA16(aw, hb[0][k], acc[j][0]);
          acc[j][1] = MFMA16(aw, hb[1][k], acc[j][1]);
        }
      }
#pragma unroll
      for (int j = 0; j < 4; ++j) {
        int p0 = (ptg + j) * 16 + lg * 4;
        f32x4 bv = bp ? *reinterpret_cast<const f32x4*>(&bp[p0]) : zero4;
#pragma unroll
        for (int nt = 0; nt < 2; ++nt) {
          int n = wv * 32 + nt * 16 + lr;
          int idx = n * 128 + (p0 ^ ((n & 7) << 3));
          us4 pk;
          if (rs) {
            us4 old = *reinterpret_cast<const us4*>(&d[idx]);
#pragma unroll
            for (int r = 0; r < 4; ++r) pk[r] = f2bf(acc[j][nt][r] + bf2f(old[r]));
          } else if (rl) {
#pragma unroll
            for (int r = 0; r < 4; ++r) {
              float v = acc[j][nt][r] + bv[r];
              pk[r] = f2bf(v > 0.f ? v : 0.f);
            }
          } else {
#pragma unroll
            for (int r = 0; r < 4; ++r) pk[r] = f2bf(acc[j][nt][r] + bv[r]);
          }
          *reinterpret_cast<us4*>(&d[idx]) = pk;
        }
      }
    }
    __syncthreads();               // all reads of wls + stores of d done
    stage_store(wreg, wls, tid);   // publish W[op+1]
    __syncthreads();
    if (op < 8) stage_load(wreg, wn, tid);  // issue W[op+2]; overlaps next compute
  }

  // ---------------- f1 (1024x128, relu) + f2 (1x1024) fused -------------------
  // h in bufB; wls holds f1 chunk0 (stored at op==8). bufA is the second
  // weight buffer. R3: per chunk, store chunk c+1 into the buffer NOT being
  // read (overlaps with MFMA), then ONE barrier, then issue load of c+2.
  {
    bf16x8 a[2][4];
#pragma unroll
    for (int nt = 0; nt < 2; ++nt) {
      int n = wv * 32 + nt * 16 + lr;
#pragma unroll
      for (int k = 0; k < 4; ++k)
        a[nt][k] = lds_frag(&bufB[n * 128 + ((k * 32 + lg * 8) ^ ((n & 7) << 3))]);
    }
    float oacc[2][4];
#pragma unroll
    for (int nt = 0; nt < 2; ++nt)
#pragma unroll
      for (int r = 0; r < 4; ++r) oacc[nt][r] = 0.f;

    stage_load(wreg, f1W + 16384, tid);  // chunk 1

#pragma unroll 1
    for (int c = 0; c < 8; ++c) {
      const unsigned short* wc = (c & 1) ? bufA : wls;   // holds chunk c
      unsigned short* wother = (c & 1) ? wls : bufA;     // gets chunk c+1
      if (c < 7) stage_store(wreg, wother, tid);         // overlapped with MFMAs
#pragma unroll
      for (int ptg = 0; ptg < 8; ptg += 2) {
        f32x4 acc[2][2];
        acc[0][0] = zero4; acc[0][1] = zero4; acc[1][0] = zero4; acc[1][1] = zero4;
#pragma unroll
        for (int k = 0; k < 4; ++k) {
#pragma unroll
          for (int j = 0; j < 2; ++j) {
            int p = (ptg + j) * 16 + lr;
            bf16x8 bw = lds_frag(&wc[p * 128 + ((k * 32 + lg * 8) ^ ((p & 7) << 3))]);
            acc[j][0] = MFMA16(a[0][k], bw, acc[j][0]);
            acc[j][1] = MFMA16(a[1][k], bw, acc[j][1]);
          }
        }
#pragma unroll
        for (int j = 0; j < 2; ++j) {
          int kg = c * 128 + (ptg + j) * 16 + lr;
          float b1 = f1b[kg];
          float w2 = f2W[kg];
#pragma unroll
          for (int nt = 0; nt < 2; ++nt) {
#pragma unroll
            for (int r = 0; r < 4; ++r) {
              float v = acc[j][nt][r] + b1;
              v = v > 0.f ? v : 0.f;
              oacc[nt][r] += v * w2;
            }
          }
        }
      }
      __syncthreads();   // chunk c+1 visible; wc reads done (c+1 overwrites it next)
      if (c < 6) stage_load(wreg, f1W + (c + 2) * 16384, tid);
    }

    // reduce partial f2 sums across the 16 column-lanes (lr), write output
#pragma unroll
    for (int msk = 1; msk < 16; msk <<= 1) {
#pragma unroll
      for (int nt = 0; nt < 2; ++nt)
#pragma unroll
        for (int r = 0; r < 4; ++r)
          oacc[nt][r] += __shfl_xor(oacc[nt][r], msk, 64);
    }
    if (lr == 0) {
      float fb = f2b[0];
#pragma unroll
      for (int nt = 0; nt < 2; ++nt)
#pragma unroll
        for (int r = 0; r < 4; ++r)
          out[b * 256 + wv * 32 + nt * 16 + lg * 4 + r] = oacc[nt][r] + fb;
    }
  }
}

extern "C" void kernel_launch(void* const* d_in, const int* in_sizes, int n_in,
                              void* d_out, int out_size, void* d_ws, size_t ws_size,
                              hipStream_t stream) {
  (void)in_sizes; (void)n_in; (void)d_ws; (void)ws_size; (void)out_size;
  fused_model<<<512, 512, 0, stream>>>(
      (const float*)d_in[0],  (const float*)d_in[1],
      (const float*)d_in[2],  (const float*)d_in[3],
      (const float*)d_in[4],  (const float*)d_in[5],
      (const float*)d_in[6],  (const float*)d_in[7],
      (const float*)d_in[8],  (const float*)d_in[9],
      (const float*)d_in[10],
      (const float*)d_in[11], (const float*)d_in[12],
      (const float*)d_in[13], (const float*)d_in[14],
      (const float*)d_in[15], (const float*)d_in[16],
      (float*)d_out);
}